// Round 7
// baseline (221.315 us; speedup 1.0000x reference)
//
#include <hip/hip_runtime.h>

#define NEMB 512
#define DIM 64
#define NB 32
#define HW 4096                    // 64*64 spatial per batch
#define NTOK (NB * HW)             // 131072 tokens
#define TPB 256
#define TOKBLK 512                 // tokens per block
#define BLOCKS (NTOK / TOKBLK)     // 256 (1 block/CU)
#define CHUNKS_PER_B (HW / TOKBLK) // 8 blocks per batch

// sumc[k] = sum_d cb[k][d]^2 — rounded squares, sequential adds (bit-exact).
__global__ void vq_sumc(const float* __restrict__ cb, float* __restrict__ sumc)
{
    int k = blockIdx.x * 256 + threadIdx.x;
    if (k < NEMB) {
#pragma clang fp contract(off)
        float s = 0.f;
#pragma unroll
        for (int d = 0; d < DIM; ++d) {
            float v = cb[k * DIM + d];
            float p = v * v;
            s = s + p;
        }
        sumc[k] = s;
    }
}

// token load + sumz: rounded squares, d-ascending sequential adds (bit-exact R2)
__device__ __forceinline__ float load_token(const float* __restrict__ zb,
                                            int hwj, float (&z)[DIM])
{
    float s = 0.f;
    {
#pragma clang fp contract(off)
#pragma unroll
        for (int d = 0; d < DIM; ++d) {
            float v = zb[(size_t)d * HW + hwj];
            z[d] = v;
            float p = v * v;
            s = s + p;
        }
    }
    return s;
}

// per-token epilogue: gather code row, straight-through out, loss partial
// (textually R2's arithmetic; z stays in regs — compile-time indices after inline)
__device__ __forceinline__ float epi_token(const float* __restrict__ cb,
                                           const float (&z)[DIM],
                                           float* __restrict__ ob,
                                           int hwj, int bk)
{
    const float4* q4 = (const float4*)(cb + (size_t)bk * DIM);
    float lsum = 0.f;
    {
#pragma clang fp contract(off)
#pragma unroll
        for (int g = 0; g < DIM / 4; ++g) {
            float4 q = q4[g];
            float qv[4] = {q.x, q.y, q.z, q.w};
#pragma unroll
            for (int j = 0; j < 4; ++j) {
                int d = g * 4 + j;
                float t1 = qv[j] - z[d];              // fl(z_q - z)
                ob[(size_t)d * HW + hwj] = z[d] + t1; // fl(z + fl(z_q - z))
                float p = t1 * t1;
                lsum = lsum + p;
            }
        }
    }
    return lsum;
}

// 4-FMA chain step, d-ascending (bit-exact chain order)
#define CH4(A, Z, C)                      \
    A = fmaf(Z[4 * g + 0], (C).x, A);     \
    A = fmaf(Z[4 * g + 1], (C).y, A);     \
    A = fmaf(Z[4 * g + 2], (C).z, A);     \
    A = fmaf(Z[4 * g + 3], (C).w, A);

// 4 tokens/thread; waves {0,1} scan codes 0..255, waves {2,3} scan 256..511
// (halves per-CU LDS broadcast traffic); argmin halves merged via LDS with
// tie-break to lower half == XLA global first-min.
__global__ __launch_bounds__(TPB, 1)
void vq_main(const float* __restrict__ z_e, const float* __restrict__ cb,
             const float* __restrict__ sumc,
             float* __restrict__ out, float* __restrict__ loss_part,
             float* __restrict__ inds_out)
{
    __shared__ float cb_s[NEMB][DIM];   // 128 KB
    __shared__ float sumc_s[NEMB];      // 2 KB
    __shared__ float bestL[2][TOKBLK];  // 4 KB
    __shared__ int   bkL[2][TOKBLK];    // 4 KB
    __shared__ float red_s[TPB];        // 1 KB   (total ~139 KB < 160)

    const int tid  = threadIdx.x;
    const int slot = tid & 127;
    const int grp  = tid >> 7;           // wave-uniform: waves 0,1 -> 0; 2,3 -> 1
    const int gid  = blockIdx.x;
    const int b    = gid / CHUNKS_PER_B;
    const int base = (gid % CHUNKS_PER_B) * TOKBLK;

    // ---- stage codebook + sumc into LDS (coalesced float4) ----
    {
        const float4* s4 = (const float4*)cb;
        float4*       d4 = (float4*)&cb_s[0][0];
#pragma unroll
        for (int i = 0; i < (NEMB * DIM / 4) / TPB; ++i)   // 32 iters
            d4[i * TPB + tid] = s4[i * TPB + tid];
        sumc_s[tid]       = sumc[tid];
        sumc_s[tid + TPB] = sumc[tid + TPB];
    }

    const float* zb = z_e + (size_t)b * DIM * HW;
    const int hw0 = base + slot;
    const int hw1 = base + 128 + slot;
    const int hw2 = base + 256 + slot;
    const int hw3 = base + 384 + slot;

    float z0[DIM], z1[DIM], z2[DIM], z3[DIM];
    const float sumz0 = load_token(zb, hw0, z0);
    const float sumz1 = load_token(zb, hw1, z1);
    const float sumz2 = load_token(zb, hw2, z2);
    const float sumz3 = load_token(zb, hw3, z3);

    __syncthreads();

    const int k0 = grp << 8;             // 0 or 256
    float best0 = 3.402823466e38f, best1 = 3.402823466e38f;
    float best2 = 3.402823466e38f, best3 = 3.402823466e38f;
    int bk0 = k0, bk1 = k0, bk2 = k0, bk3 = k0;

    for (int kk = 0; kk < NEMB / 2; kk += 2) {
        const int k = k0 + kk;
        const float4* c0 = (const float4*)&cb_s[k][0];
        const float4* c1 = (const float4*)&cb_s[k + 1][0];
        float a00 = 0.f, a01 = 0.f, a10 = 0.f, a11 = 0.f;
        float a20 = 0.f, a21 = 0.f, a30 = 0.f, a31 = 0.f;
#pragma unroll
        for (int g = 0; g < DIM / 4; ++g) {
            float4 u = c0[g];
            float4 v = c1[g];
            CH4(a00, z0, u) CH4(a01, z0, v)
            CH4(a10, z1, u) CH4(a11, z1, v)
            CH4(a20, z2, u) CH4(a21, z2, v)
            CH4(a30, z3, u) CH4(a31, z3, v)
        }
        // same source expression / pragma context as the bit-exact R2 loop
        float d2a0 = (sumz0 - 2.0f * a00) + sumc_s[k];
        float d2b0 = (sumz0 - 2.0f * a01) + sumc_s[k + 1];
        float d2a1 = (sumz1 - 2.0f * a10) + sumc_s[k];
        float d2b1 = (sumz1 - 2.0f * a11) + sumc_s[k + 1];
        float d2a2 = (sumz2 - 2.0f * a20) + sumc_s[k];
        float d2b2 = (sumz2 - 2.0f * a21) + sumc_s[k + 1];
        float d2a3 = (sumz3 - 2.0f * a30) + sumc_s[k];
        float d2b3 = (sumz3 - 2.0f * a31) + sumc_s[k + 1];
        if (d2a0 < best0) { best0 = d2a0; bk0 = k; }
        if (d2b0 < best0) { best0 = d2b0; bk0 = k + 1; }
        if (d2a1 < best1) { best1 = d2a1; bk1 = k; }
        if (d2b1 < best1) { best1 = d2b1; bk1 = k + 1; }
        if (d2a2 < best2) { best2 = d2a2; bk2 = k; }
        if (d2b2 < best2) { best2 = d2b2; bk2 = k + 1; }
        if (d2a3 < best3) { best3 = d2a3; bk3 = k; }
        if (d2b3 < best3) { best3 = d2b3; bk3 = k + 1; }
    }

    // ---- exchange per-half argmins ----
    bestL[grp][slot]       = best0;  bkL[grp][slot]       = bk0;
    bestL[grp][128 + slot] = best1;  bkL[grp][128 + slot] = bk1;
    bestL[grp][256 + slot] = best2;  bkL[grp][256 + slot] = bk2;
    bestL[grp][384 + slot] = best3;  bkL[grp][384 + slot] = bk3;
    __syncthreads();

    // thread tid finalizes block-tokens j0 = tid (tree0) and j1 = 256+tid (tree1).
    const int j0 = tid;
    const int j1 = 256 + tid;
    // merge: lower half wins ties (all its k are smaller) == global first-min
    float bA0 = bestL[0][j0], bB0 = bestL[1][j0];
    int   mk0 = (bB0 < bA0) ? bkL[1][j0] : bkL[0][j0];
    float bA1 = bestL[0][j1], bB1 = bestL[1][j1];
    int   mk1 = (bB1 < bA1) ? bkL[1][j1] : bkL[0][j1];

    inds_out[(size_t)gid * TOKBLK + j0] = (float)mk0;
    inds_out[(size_t)gid * TOKBLK + j1] = (float)mk1;

    // epilogue: z for j0/j1 lives in this thread's regs (m = grp-dependent,
    // wave-uniform branch keeps indices compile-time)
    float* ob = out + (size_t)b * DIM * HW;
    float lsumA, lsumB;
    if (grp == 0) {   // j0 = slot -> z0 ; j1 = 256+slot -> z2
        lsumA = epi_token(cb, z0, ob, base + j0, mk0);
        lsumB = epi_token(cb, z2, ob, base + j1, mk1);
    } else {          // j0 = 128+slot -> z1 ; j1 = 384+slot -> z3
        lsumA = epi_token(cb, z1, ob, base + j0, mk0);
        lsumB = epi_token(cb, z3, ob, base + j1, mk1);
    }

    // ---- two 256-leaf trees -> 2 partials/block (R2's exact association) ----
    __syncthreads();
    red_s[tid] = lsumA;
    __syncthreads();
#pragma unroll
    for (int s = TPB / 2; s > 0; s >>= 1) {
        if (tid < s) red_s[tid] = red_s[tid] + red_s[tid + s];
        __syncthreads();
    }
    if (tid == 0) loss_part[2 * gid] = red_s[0];
    __syncthreads();
    red_s[tid] = lsumB;
    __syncthreads();
#pragma unroll
    for (int s = TPB / 2; s > 0; s >>= 1) {
        if (tid < s) red_s[tid] = red_s[tid] + red_s[tid + s];
        __syncthreads();
    }
    if (tid == 0) loss_part[2 * gid + 1] = red_s[0];
}

// deterministic final reduce: 16 partials per batch, fixed order (== R2)
__global__ void vq_loss_final(const float* __restrict__ part,
                              float* __restrict__ loss_out)
{
    int b = threadIdx.x;
    if (b < NB) {
        float s = 0.f;
        for (int i = 0; i < 16; ++i)
            s = s + part[b * 16 + i];
        float m = s * (1.0f / (HW * DIM));   // exact /2^18
        loss_out[b] = m + 0.25f * m;
    }
}

extern "C" void kernel_launch(void* const* d_in, const int* in_sizes, int n_in,
                              void* d_out, int out_size, void* d_ws, size_t ws_size,
                              hipStream_t stream)
{
    const float* z_e = (const float*)d_in[0];
    const float* cb  = (const float*)d_in[1];

    float* out  = (float*)d_out;
    float* loss = out + (size_t)NB * DIM * HW;  // offset 8388608
    float* inds = loss + NB;                    // offset 8388640

    float* part  = (float*)d_ws;                // [512] loss partials
    float* sumcg = part + 512;                  // [512] codebook row norms

    vq_sumc<<<2, TPB, 0, stream>>>(cb, sumcg);
    vq_main<<<BLOCKS, TPB, 0, stream>>>(z_e, cb, sumcg, out, part, inds);
    vq_loss_final<<<1, 64, 0, stream>>>(part, loss);
}

// Round 8
// 191.608 us; speedup vs baseline: 1.1550x; 1.1550x over previous
//
#include <hip/hip_runtime.h>

#define NEMB 512
#define DIM 64
#define NB 32
#define HW 4096                   // 64*64 spatial per batch
#define NTOK (NB * HW)            // 131072 tokens
#define TPB 256
#define TPT 2                     // tokens per thread
#define TOK_PER_BLK (TPB * TPT)   // 512
#define BLOCKS (NTOK / TOK_PER_BLK)     // 256  (1 block/CU)
#define CHUNKS_PER_B (HW / TOK_PER_BLK) // 8 blocks per batch

// sumc[k] = sum_d cb[k][d]^2 — rounded squares, sequential adds (bit-exact R2).
__global__ void vq_sumc(const float* __restrict__ cb, float* __restrict__ sumc)
{
    int k = blockIdx.x * 256 + threadIdx.x;
    if (k < NEMB) {
#pragma clang fp contract(off)
        float s = 0.f;
#pragma unroll
        for (int d = 0; d < DIM; ++d) {
            float v = cb[k * DIM + d];
            float p = v * v;
            s = s + p;
        }
        sumc[k] = s;
    }
}

// 2 tokens/thread; full codebook in LDS; SINGLE-k loop with half-row
// ping-pong prefetch (A=lo half, B=hi half) so ds_read latency hides under
// the previous half's 64 FMAs. All rounding-sensitive orders identical to
// the bit-exact R2/R6 kernels (d-ascending chains, same d2 expression,
// strict-< ascending-k argmin).
__global__ __launch_bounds__(TPB, 1)
void vq_main(const float* __restrict__ z_e, const float* __restrict__ cb,
             const float* __restrict__ sumc,
             float* __restrict__ out, float* __restrict__ loss_part,
             float* __restrict__ inds_out)
{
    __shared__ float cb_s[NEMB + 1][DIM];   // 128 KB + 1 pad row (prefetch overrun)
    __shared__ float sumc_s[NEMB];          // 2 KB
    __shared__ float red_s[TPB];            // 1 KB

    const int tid  = threadIdx.x;
    const int gid  = blockIdx.x;
    const int b    = gid / CHUNKS_PER_B;
    const int base = (gid % CHUNKS_PER_B) * TOK_PER_BLK;
    const int hw0  = base + tid;          // token A
    const int hw1  = base + TPB + tid;    // token B

    // ---- stage codebook + sumc into LDS (coalesced float4) ----
    {
        const float4* s4 = (const float4*)cb;
#pragma unroll
        for (int i = 0; i < (NEMB * DIM / 4) / TPB; ++i) {  // 32 iters
            int idx = i * TPB + tid;
            int row = idx >> 4;          // 16 float4 per row
            int col = idx & 15;
            ((float4*)&cb_s[row][0])[col] = s4[idx];
        }
        sumc_s[tid]       = sumc[tid];
        sumc_s[tid + TPB] = sumc[tid + TPB];
    }

    const float* zb = z_e + (size_t)b * DIM * HW;

    // ---- tokens into registers; sumz rounded-squares, d-ascending ----
    float z0[DIM], z1[DIM];
    float sumz0 = 0.f, sumz1 = 0.f;
    {
#pragma clang fp contract(off)
#pragma unroll
        for (int d = 0; d < DIM; ++d) {
            float v = zb[(size_t)d * HW + hw0];
            z0[d] = v;
            float p = v * v;
            sumz0 = sumz0 + p;
        }
#pragma unroll
        for (int d = 0; d < DIM; ++d) {
            float v = zb[(size_t)d * HW + hw1];
            z1[d] = v;
            float p = v * v;
            sumz1 = sumz1 + p;
        }
    }

    __syncthreads();

    float best0 = 3.402823466e38f, best1 = 3.402823466e38f;
    int   bk0 = 0, bk1 = 0;

    float4 A[8], B[8];
    {   // prologue: A <- lo half of row 0
        const float4* r0 = (const float4*)&cb_s[0][0];
#pragma unroll
        for (int g = 0; g < 8; ++g) A[g] = r0[g];
    }

    for (int k = 0; k < NEMB; ++k) {
        const float4* hi_cur  = (const float4*)&cb_s[k][0] + 8;
        const float4* lo_next = (const float4*)&cb_s[k + 1][0];

        // issue hi(k) -> B (consumed after A's FMAs: latency hidden)
#pragma unroll
        for (int g = 0; g < 8; ++g) B[g] = hi_cur[g];

        // lo-half FMAs on A: chains d-ascending (bit-exact order)
        float a0 = 0.f, a1 = 0.f;
#pragma unroll
        for (int g = 0; g < 8; ++g) {
            float4 u = A[g];
            a0 = fmaf(z0[4 * g + 0], u.x, a0);
            a0 = fmaf(z0[4 * g + 1], u.y, a0);
            a0 = fmaf(z0[4 * g + 2], u.z, a0);
            a0 = fmaf(z0[4 * g + 3], u.w, a0);
            a1 = fmaf(z1[4 * g + 0], u.x, a1);
            a1 = fmaf(z1[4 * g + 1], u.y, a1);
            a1 = fmaf(z1[4 * g + 2], u.z, a1);
            a1 = fmaf(z1[4 * g + 3], u.w, a1);
        }

        // issue lo(k+1) -> A (consumed next iter; hidden under B's FMAs)
#pragma unroll
        for (int g = 0; g < 8; ++g) A[g] = lo_next[g];

        // hi-half FMAs on B (d = 32..63, ascending)
#pragma unroll
        for (int g = 0; g < 8; ++g) {
            float4 u = B[g];
            a0 = fmaf(z0[32 + 4 * g + 0], u.x, a0);
            a0 = fmaf(z0[32 + 4 * g + 1], u.y, a0);
            a0 = fmaf(z0[32 + 4 * g + 2], u.z, a0);
            a0 = fmaf(z0[32 + 4 * g + 3], u.w, a0);
            a1 = fmaf(z1[32 + 4 * g + 0], u.x, a1);
            a1 = fmaf(z1[32 + 4 * g + 1], u.y, a1);
            a1 = fmaf(z1[32 + 4 * g + 2], u.z, a1);
            a1 = fmaf(z1[32 + 4 * g + 3], u.w, a1);
        }

        // same source expression as the bit-exact R2/R6 loop; compares in
        // ascending-k order (global sequence identical)
        float d2a = (sumz0 - 2.0f * a0) + sumc_s[k];
        float d2b = (sumz1 - 2.0f * a1) + sumc_s[k];
        if (d2a < best0) { best0 = d2a; bk0 = k; }
        if (d2b < best1) { best1 = d2b; bk1 = k; }
    }

    // ---- epilogue (textually R6) ----
    inds_out[(size_t)gid * TOK_PER_BLK + tid]       = (float)bk0;
    inds_out[(size_t)gid * TOK_PER_BLK + TPB + tid] = (float)bk1;

    float* ob = out + (size_t)b * DIM * HW;
    float lsum0 = 0.f, lsum1 = 0.f;
    const float4* q4a = (const float4*)(cb + (size_t)bk0 * DIM);
    const float4* q4b = (const float4*)(cb + (size_t)bk1 * DIM);
    {
#pragma clang fp contract(off)
#pragma unroll
        for (int g = 0; g < DIM / 4; ++g) {
            float4 q = q4a[g];
            float qv[4] = {q.x, q.y, q.z, q.w};
#pragma unroll
            for (int j = 0; j < 4; ++j) {
                int d = g * 4 + j;
                float t1 = qv[j] - z0[d];              // fl(z_q - z)
                ob[(size_t)d * HW + hw0] = z0[d] + t1; // fl(z + fl(z_q - z))
                float p = t1 * t1;
                lsum0 = lsum0 + p;
            }
        }
    }
    {
#pragma clang fp contract(off)
#pragma unroll
        for (int g = 0; g < DIM / 4; ++g) {
            float4 q = q4b[g];
            float qv[4] = {q.x, q.y, q.z, q.w};
#pragma unroll
            for (int j = 0; j < 4; ++j) {
                int d = g * 4 + j;
                float t1 = qv[j] - z1[d];
                ob[(size_t)d * HW + hw1] = z1[d] + t1;
                float p = t1 * t1;
                lsum1 = lsum1 + p;
            }
        }
    }

    // ---- two 256-leaf trees -> 2 partials/block == R2's exact association ----
    __syncthreads();
    red_s[tid] = lsum0;
    __syncthreads();
#pragma unroll
    for (int s = TPB / 2; s > 0; s >>= 1) {
        if (tid < s) red_s[tid] = red_s[tid] + red_s[tid + s];
        __syncthreads();
    }
    if (tid == 0) loss_part[2 * gid] = red_s[0];
    __syncthreads();
    red_s[tid] = lsum1;
    __syncthreads();
#pragma unroll
    for (int s = TPB / 2; s > 0; s >>= 1) {
        if (tid < s) red_s[tid] = red_s[tid] + red_s[tid + s];
        __syncthreads();
    }
    if (tid == 0) loss_part[2 * gid + 1] = red_s[0];
}

// deterministic final reduce: 16 partials per batch, fixed order (== R2)
__global__ void vq_loss_final(const float* __restrict__ part,
                              float* __restrict__ loss_out)
{
    int b = threadIdx.x;
    if (b < NB) {
        float s = 0.f;
        for (int i = 0; i < 16; ++i)
            s = s + part[b * 16 + i];
        float m = s * (1.0f / (HW * DIM));   // exact /2^18
        loss_out[b] = m + 0.25f * m;
    }
}

extern "C" void kernel_launch(void* const* d_in, const int* in_sizes, int n_in,
                              void* d_out, int out_size, void* d_ws, size_t ws_size,
                              hipStream_t stream)
{
    const float* z_e = (const float*)d_in[0];
    const float* cb  = (const float*)d_in[1];

    float* out  = (float*)d_out;
    float* loss = out + (size_t)NB * DIM * HW;  // offset 8388608
    float* inds = loss + NB;                    // offset 8388640

    float* part  = (float*)d_ws;                // [512] loss partials
    float* sumcg = part + 512;                  // [512] codebook row norms

    vq_sumc<<<2, TPB, 0, stream>>>(cb, sumcg);
    vq_main<<<BLOCKS, TPB, 0, stream>>>(z_e, cb, sumcg, out, part, inds);
    vq_loss_final<<<1, 64, 0, stream>>>(part, loss);
}

// Round 10
// 97.436 us; speedup vs baseline: 2.2714x; 1.9665x over previous
//
#include <hip/hip_runtime.h>

#define NEMB 512
#define DIM 64
#define NB 32
#define HW 4096
#define NTOK (NB * HW)            // 131072
#define TPB 512                   // 8 waves
#define TOKBLK 512                // tokens per block
#define BLOCKS (NTOK / TOKBLK)    // 256

typedef float f32x16 __attribute__((ext_vector_type(16)));
typedef short bf16x8 __attribute__((ext_vector_type(8)));

// ws float-offsets
#define WS_PART 0                 // [512] loss partials
#define WS_SUMC 512               // [512] exact row norms
#define WS_CMAX 1024              // max |c| over codebook
#define WS_SCMAX 1025             // max sumc
#define WS_CH 1040                // u32[512*32] packed bf16-hi (16B aligned)
#define WS_CL (1040 + 16384)      // u32[512*32] packed bf16-lo

// RNE float->bf16 (self-contained, deterministic; inputs finite)
__device__ __forceinline__ unsigned short f2bf(float f) {
    unsigned u = __float_as_uint(f);
    unsigned r = u + 0x7FFFu + ((u >> 16) & 1u);
    return (unsigned short)(r >> 16);
}
__device__ __forceinline__ float bf2f(unsigned short h) {
    return __uint_as_float((unsigned)h << 16);
}

// prep: exact sumc (R2 order) + bf16 hi/lo split (packed) + cmax/sumcmax
__global__ void vq_prep(const float* __restrict__ cb, float* __restrict__ ws)
{
    __shared__ float redm[256], redsc[256];
    const int tid = threadIdx.x;
    float cmax_t = 0.f, scmax_t = 0.f;
    for (int rep = 0; rep < 2; ++rep) {
        int k = rep * 256 + tid;
        {   // exact sumc: rounded squares, sequential adds (bit-exact R2)
#pragma clang fp contract(off)
            float s = 0.f;
#pragma unroll
            for (int d = 0; d < DIM; ++d) {
                float v = cb[k * DIM + d];
                float p = v * v;
                s = s + p;
            }
            ws[WS_SUMC + k] = s;
            scmax_t = fmaxf(scmax_t, s);
        }
        unsigned* chp = (unsigned*)(ws + WS_CH) + k * 32;
        unsigned* clp = (unsigned*)(ws + WS_CL) + k * 32;
#pragma unroll
        for (int q = 0; q < 32; ++q) {
            float v0 = cb[k * DIM + 2 * q], v1 = cb[k * DIM + 2 * q + 1];
            cmax_t = fmaxf(cmax_t, fmaxf(fabsf(v0), fabsf(v1)));
            unsigned short h0 = f2bf(v0), h1 = f2bf(v1);
            unsigned short l0 = f2bf(v0 - bf2f(h0)), l1 = f2bf(v1 - bf2f(h1));
            chp[q] = (unsigned)h0 | ((unsigned)h1 << 16);
            clp[q] = (unsigned)l0 | ((unsigned)l1 << 16);
        }
    }
    redm[tid] = cmax_t; redsc[tid] = scmax_t;
    __syncthreads();
    for (int s = 128; s > 0; s >>= 1) {
        if (tid < s) {
            redm[tid]  = fmaxf(redm[tid],  redm[tid + s]);
            redsc[tid] = fmaxf(redsc[tid], redsc[tid + s]);
        }
        __syncthreads();
    }
    if (tid == 0) { ws[WS_CMAX] = redm[0]; ws[WS_SCMAX] = redsc[0]; }
}

// main: MFMA bf16-split filter (A=codes, B=tokens) + exact fp32 re-rank.
__global__ __launch_bounds__(TPB, 2)
void vq_main(const float* __restrict__ z_e, const float* __restrict__ cb,
             const float* __restrict__ ws, float* __restrict__ out,
             float* __restrict__ loss_part, float* __restrict__ inds_out)
{
    __shared__ uint4 ch_s[NEMB * 9];   // 72 KB, rotation-swizzled blocks
    __shared__ uint4 cl_s[NEMB * 9];   // 72 KB
    __shared__ float sumc_s[NEMB];     // 2 KB
    __shared__ float red_s[TPB];       // 2 KB
    __shared__ float sc2[2];

    const int tid  = threadIdx.x;
    const int gid  = blockIdx.x;
    const int b    = gid >> 3;
    const int base = (gid & 7) * TOKBLK;
    const int w    = tid >> 6;
    const int l    = tid & 63;
    const int col  = l & 31;
    const int half = l >> 5;

    // ---- stage swizzled bf16 codebook + sumc ----
    {
        const uint4* chg = (const uint4*)(ws + WS_CH);
        const uint4* clg = (const uint4*)(ws + WS_CL);
#pragma unroll
        for (int i = 0; i < 8; ++i) {
            int idx = i * TPB + tid;          // 0..4095
            int c = idx >> 3, bd = idx & 7;
            int slot = (bd + c) & 7;          // rotation swizzle (~2-way banks)
            ch_s[c * 9 + slot] = chg[idx];
            cl_s[c * 9 + slot] = clg[idx];
        }
        sumc_s[tid] = ws[WS_SUMC + tid];
        if (tid < 2) sc2[tid] = ws[WS_CMAX + tid];
    }

    // ---- z B-frags (bf16 hi/lo) + L1z / approx sumz ----
    const float* zb = z_e + (size_t)b * DIM * HW;
    const int t0 = base + w * 64;
    uint4 bzh[2][4], bzl[2][4];
    float l1p[2] = {0.f, 0.f}, szp[2] = {0.f, 0.f};
#pragma unroll
    for (int tt = 0; tt < 2; ++tt) {
        int tok = t0 + tt * 32 + col;
#pragma unroll
        for (int ks = 0; ks < 4; ++ks) {
            unsigned hh[8], ll[8];
#pragma unroll
            for (int j = 0; j < 8; ++j) {
                int d = 16 * ks + 8 * half + j;
                float v = zb[(size_t)d * HW + tok];
                l1p[tt] += fabsf(v);
                szp[tt] = fmaf(v, v, szp[tt]);
                unsigned short h = f2bf(v);
                unsigned short lo = f2bf(v - bf2f(h));
                hh[j] = h; ll[j] = lo;
            }
            bzh[tt][ks] = make_uint4(hh[0] | (hh[1] << 16), hh[2] | (hh[3] << 16),
                                     hh[4] | (hh[5] << 16), hh[6] | (hh[7] << 16));
            bzl[tt][ks] = make_uint4(ll[0] | (ll[1] << 16), ll[2] | (ll[3] << 16),
                                     ll[4] | (ll[5] << 16), ll[6] | (ll[7] << 16));
        }
    }
    float L1[2], SZ[2];
#pragma unroll
    for (int tt = 0; tt < 2; ++tt) {
        L1[tt] = l1p[tt] + __shfl_xor(l1p[tt], 32);
        SZ[tt] = szp[tt] + __shfl_xor(szp[tt], 32);
    }
    __syncthreads();

    const float cmax = sc2[0], scmax = sc2[1];
    float gapd[2];
#pragma unroll
    for (int tt = 0; tt < 2; ++tt)
        gapd[tt] = 1.2e-4f * cmax * L1[tt] + 0.5f * scmax + 1.2e-7f * SZ[tt] + 1e-6f;

    // ---- MFMA filter: D[code][token], 3 split passes ----
    unsigned mask0[8], mask1[8];
#pragma unroll
    for (int i = 0; i < 8; ++i) { mask0[i] = 0u; mask1[i] = 0u; }
    float runm[2] = {-3.402823466e38f, -3.402823466e38f};

    for (int ct = 0; ct < 16; ++ct) {
        bf16x8 ah[4], al[4];
        const int c = 32 * ct + col;
        const int rowb = c * 9;
#pragma unroll
        for (int ks = 0; ks < 4; ++ks) {
            int slot = ((2 * ks + half) + c) & 7;
            uint4 u1 = ch_s[rowb + slot];
            uint4 u2 = cl_s[rowb + slot];
            ah[ks] = *(bf16x8*)&u1;
            al[ks] = *(bf16x8*)&u2;
        }
#pragma unroll
        for (int tt = 0; tt < 2; ++tt) {
            f32x16 acc = {0.f, 0.f, 0.f, 0.f, 0.f, 0.f, 0.f, 0.f,
                          0.f, 0.f, 0.f, 0.f, 0.f, 0.f, 0.f, 0.f};
#pragma unroll
            for (int ks = 0; ks < 4; ++ks)
                acc = __builtin_amdgcn_mfma_f32_32x32x16_bf16(ah[ks], *(bf16x8*)&bzh[tt][ks], acc, 0, 0, 0);
#pragma unroll
            for (int ks = 0; ks < 4; ++ks)
                acc = __builtin_amdgcn_mfma_f32_32x32x16_bf16(al[ks], *(bf16x8*)&bzh[tt][ks], acc, 0, 0, 0);
#pragma unroll
            for (int ks = 0; ks < 4; ++ks)
                acc = __builtin_amdgcn_mfma_f32_32x32x16_bf16(ah[ks], *(bf16x8*)&bzl[tt][ks], acc, 0, 0, 0);
            float m = acc[0];
#pragma unroll
            for (int r = 1; r < 16; ++r) m = fmaxf(m, acc[r]);
            float rm = fmaxf(tt == 0 ? runm[0] : runm[1], m);
            if (tt == 0) runm[0] = rm; else runm[1] = rm;
            float thr = rm - (tt == 0 ? gapd[0] : gapd[1]);
            unsigned bits = 0;
#pragma unroll
            for (int r = 0; r < 16; ++r)
                bits |= (acc[r] >= thr) ? (1u << r) : 0u;
            unsigned sh = bits << ((ct & 1) * 16);
            if (tt == 0) mask0[ct >> 1] |= sh; else mask1[ct >> 1] |= sh;
        }
    }

    // ---- exchange halves: owner lane l owns in-wave token l (ttile=half) ----
    unsigned om[8], xm[8];
#pragma unroll
    for (int i = 0; i < 8; ++i) {
        om[i] = half ? mask1[i] : mask0[i];
        xm[i] = __shfl_xor(half ? mask0[i] : mask1[i], 32);
    }

    // ---- phase B: exact reload + re-rank (textually R2) ----
    const int hwme = base + tid;
    float z[DIM];
    float sumz;
    {
#pragma clang fp contract(off)
        sumz = 0.f;
#pragma unroll
        for (int d = 0; d < DIM; ++d) {
            float v = zb[(size_t)d * HW + hwme];
            z[d] = v;
            float p = v * v;
            sumz = sumz + p;
        }
    }

    float best = 3.402823466e38f;
    int bk = 0;
    for (int ct = 0; ct < 16; ++ct) {
        unsigned A = (om[ct >> 1] >> ((ct & 1) * 16)) & 0xFFFFu;
        unsigned B = (xm[ct >> 1] >> ((ct & 1) * 16)) & 0xFFFFu;
        // deposit: bit r -> kk = (r&3) + 4*h_src + 8*(r>>2)
        unsigned wo = ((A & 0xFu)) | (((A >> 4) & 0xFu) << 8) |
                      (((A >> 8) & 0xFu) << 16) | (((A >> 12) & 0xFu) << 24);
        unsigned wx = ((B & 0xFu)) | (((B >> 4) & 0xFu) << 8) |
                      (((B >> 8) & 0xFu) << 16) | (((B >> 12) & 0xFu) << 24);
        unsigned wc = half ? ((wo << 4) | wx) : (wo | (wx << 4));
        while (wc) {
            int kk = __builtin_ctz(wc);
            wc &= wc - 1;
            int k = 32 * ct + kk;
            const float4* c4 = (const float4*)(cb + (size_t)k * DIM);
            float a0 = 0.f;
#pragma unroll
            for (int g = 0; g < DIM / 4; ++g) {
                float4 u = c4[g];
                a0 = fmaf(z[4 * g + 0], u.x, a0);
                a0 = fmaf(z[4 * g + 1], u.y, a0);
                a0 = fmaf(z[4 * g + 2], u.z, a0);
                a0 = fmaf(z[4 * g + 3], u.w, a0);
            }
            float d2 = (sumz - 2.0f * a0) + sumc_s[k];
            if (d2 < best) { best = d2; bk = k; }
        }
    }

    // ---- epilogue (textually R2) ----
    inds_out[(size_t)gid * TOKBLK + tid] = (float)bk;
    float* ob = out + (size_t)b * DIM * HW;
    float lsum = 0.f;
    const float4* q4 = (const float4*)(cb + (size_t)bk * DIM);
    {
#pragma clang fp contract(off)
#pragma unroll
        for (int g = 0; g < DIM / 4; ++g) {
            float4 qq = q4[g];
            float qv[4] = {qq.x, qq.y, qq.z, qq.w};
#pragma unroll
            for (int j = 0; j < 4; ++j) {
                int d = g * 4 + j;
                float t1 = qv[j] - z[d];               // fl(z_q - z)
                ob[(size_t)d * HW + hwme] = z[d] + t1; // fl(z + fl(z_q - z))
                float p = t1 * t1;
                lsum = lsum + p;
            }
        }
    }

    // ---- two 256-leaf trees (R2's exact association) ----
    __syncthreads();
    red_s[tid] = lsum;
    __syncthreads();
#pragma unroll
    for (int s = 128; s > 0; s >>= 1) {
        if ((tid & 255) < s) red_s[tid] = red_s[tid] + red_s[tid + s];
        __syncthreads();
    }
    if (tid == 0)   loss_part[2 * gid]     = red_s[0];
    if (tid == 256) loss_part[2 * gid + 1] = red_s[256];
}

// deterministic final reduce: 16 partials per batch, fixed order (== R2)
__global__ void vq_loss_final(const float* __restrict__ part,
                              float* __restrict__ loss_out)
{
    int b = threadIdx.x;
    if (b < NB) {
        float s = 0.f;
        for (int i = 0; i < 16; ++i)
            s = s + part[b * 16 + i];
        float m = s * (1.0f / (HW * DIM));   // exact /2^18
        loss_out[b] = m + 0.25f * m;
    }
}

extern "C" void kernel_launch(void* const* d_in, const int* in_sizes, int n_in,
                              void* d_out, int out_size, void* d_ws, size_t ws_size,
                              hipStream_t stream)
{
    const float* z_e = (const float*)d_in[0];
    const float* cb  = (const float*)d_in[1];

    float* out  = (float*)d_out;
    float* loss = out + (size_t)NB * DIM * HW;  // 8388608
    float* inds = loss + NB;                    // 8388640
    float* ws   = (float*)d_ws;

    vq_prep<<<1, 256, 0, stream>>>(cb, ws);
    vq_main<<<BLOCKS, TPB, 0, stream>>>(z_e, cb, ws, out, ws + WS_PART, inds);
    vq_loss_final<<<1, 64, 0, stream>>>(ws + WS_PART, loss);
}